// Round 2
// baseline (138.989 us; speedup 1.0000x reference)
//
#include <hip/hip_runtime.h>

// SimpleMHA2D: B=32, S=HW=1024, C=KV=1024, N=16, K=V=64, fp32.
//  K1: qk[c][n] = sum_k k_kernel[c][n*64+k]*q[n][k];  qb[n] = sum_k k_bias*q
//  K2: logits[b][n][s] = x[b,s,:] . qk[:,n] + qb[n]   (LDS-staged skinny GEMM)
//  K3: per (b,n): m = max_s, e[b][s][n] = exp(l-m), l_sum
//  K4: wp[b][ch][n][c] = sum_{s in chunk} e[b][s][n]*x[b,s,c]
//  K5: out[b][n][v] = (sum_ch wp . vk[:, n*64+v]) / l_sum + vb[n*64+v]

// ---------------- K1: fold query into k_kernel ----------------
__global__ __launch_bounds__(256) void k_qk(const float* __restrict__ kk,
                                            const float* __restrict__ q,
                                            const float* __restrict__ kb,
                                            float* __restrict__ qk,
                                            float* __restrict__ qb) {
  const int gid = blockIdx.x * 256 + threadIdx.x;   // 16384 = 1024c * 16n
  const int c = gid >> 4, n = gid & 15;
  float a = 0.f;
#pragma unroll
  for (int k4 = 0; k4 < 64; k4 += 4) {
    const float4 kv = *(const float4*)(kk + (size_t)c * 1024 + n * 64 + k4);
    const float4 qv = *(const float4*)(q + n * 64 + k4);
    a += kv.x * qv.x + kv.y * qv.y + kv.z * qv.z + kv.w * qv.w;
  }
  qk[gid] = a;  // layout [c][n], gid == c*16+n
  if (blockIdx.x == 0 && threadIdx.x < 16) {
    float s = 0.f;
    for (int k = 0; k < 64; k++) s += kb[threadIdx.x * 64 + k] * q[threadIdx.x * 64 + k];
    qb[threadIdx.x] = s;
  }
}

// ---------------- K2: logits_t[b][n][s] = x . qk + qb ----------------
// Block: 256 thr, 64 rows (s), c in 8 chunks of 128. LDS tile [64][129]
// (odd pitch -> conflict-free lane<->row scalar reads). Wave w covers
// c-quarter; qk read at wave-uniform address (scalar-load path).
__global__ __launch_bounds__(256) void k_logits(const float* __restrict__ x,
                                                const float* __restrict__ qk,
                                                const float* __restrict__ qb,
                                                float* __restrict__ lg) {
  __shared__ float tl[64 * 129];  // 33 KB; reduce buffer overlaid at end
  const int tid = threadIdx.x;
  const int lane = tid & 63;
  const int wid = __builtin_amdgcn_readfirstlane(tid >> 6);
  const int row0 = blockIdx.x * 64;   // global row in [0, 32768)
  const int b = row0 >> 10, s0 = row0 & 1023;
  const float* xb = x + (size_t)row0 * 1024;

  float4 rbuf[8];
  // prologue: stage chunk 0
#pragma unroll
  for (int k = 0; k < 8; ++k) {
    const int f = k * 256 + tid;          // float4 index: row=f>>5, col4=f&31
    rbuf[k] = *(const float4*)(xb + (size_t)(f >> 5) * 1024 + (f & 31) * 4);
  }
#pragma unroll
  for (int k = 0; k < 8; ++k) {
    const int f = k * 256 + tid;
    const int r = f >> 5, c4 = (f & 31) * 4;
    tl[r * 129 + c4 + 0] = rbuf[k].x;
    tl[r * 129 + c4 + 1] = rbuf[k].y;
    tl[r * 129 + c4 + 2] = rbuf[k].z;
    tl[r * 129 + c4 + 3] = rbuf[k].w;
  }
  __syncthreads();

  float acc[16];
#pragma unroll
  for (int n = 0; n < 16; ++n) acc[n] = 0.f;
  const int wl0 = wid * 32;  // wave's c-offset within chunk (uniform)

#pragma unroll 1
  for (int ch = 0; ch < 8; ++ch) {
    // issue next chunk's global loads early (latency hides under compute)
    if (ch < 7) {
      const int cbase = (ch + 1) * 128;
#pragma unroll
      for (int k = 0; k < 8; ++k) {
        const int f = k * 256 + tid;
        rbuf[k] = *(const float4*)(xb + (size_t)(f >> 5) * 1024 + cbase + (f & 31) * 4);
      }
    }
    // compute: lane <-> row; wave covers c in [wl0, wl0+32)
    const float* qrow = qk + (size_t)(ch * 128 + wl0) * 16;  // wave-uniform
    const float* xrow = tl + lane * 129 + wl0;
#pragma unroll
    for (int cc = 0; cc < 32; ++cc) {
      const float xs = xrow[cc];
      const float* qr = qrow + cc * 16;
      const float4 q0 = ((const float4*)qr)[0];
      const float4 q1 = ((const float4*)qr)[1];
      const float4 q2 = ((const float4*)qr)[2];
      const float4 q3 = ((const float4*)qr)[3];
      acc[0]  += xs * q0.x; acc[1]  += xs * q0.y; acc[2]  += xs * q0.z; acc[3]  += xs * q0.w;
      acc[4]  += xs * q1.x; acc[5]  += xs * q1.y; acc[6]  += xs * q1.z; acc[7]  += xs * q1.w;
      acc[8]  += xs * q2.x; acc[9]  += xs * q2.y; acc[10] += xs * q2.z; acc[11] += xs * q2.w;
      acc[12] += xs * q3.x; acc[13] += xs * q3.y; acc[14] += xs * q3.z; acc[15] += xs * q3.w;
    }
    __syncthreads();  // all waves done reading tl
    if (ch < 7) {
#pragma unroll
      for (int k = 0; k < 8; ++k) {
        const int f = k * 256 + tid;
        const int r = f >> 5, c4 = (f & 31) * 4;
        tl[r * 129 + c4 + 0] = rbuf[k].x;
        tl[r * 129 + c4 + 1] = rbuf[k].y;
        tl[r * 129 + c4 + 2] = rbuf[k].z;
        tl[r * 129 + c4 + 3] = rbuf[k].w;
      }
    }
    __syncthreads();  // writes visible
  }

  // cross-wave reduce: part[w][row][16] overlaid on tl (4096 floats < 8256)
  float* part = tl;
#pragma unroll
  for (int n0 = 0; n0 < 16; n0 += 4) {
    float4 v = make_float4(acc[n0], acc[n0 + 1], acc[n0 + 2], acc[n0 + 3]);
    *(float4*)&part[(wid * 64 + lane) * 16 + n0] = v;
  }
  __syncthreads();
  {
    const int r = tid >> 2, n0 = (tid & 3) * 4;
    float4 s = make_float4(0.f, 0.f, 0.f, 0.f);
#pragma unroll
    for (int w = 0; w < 4; ++w) {
      const float4 p = *(const float4*)&part[(w * 64 + r) * 16 + n0];
      s.x += p.x; s.y += p.y; s.z += p.z; s.w += p.w;
    }
    const float4 qbv = *(const float4*)(qb + n0);
    lg[(size_t)(b * 16 + n0 + 0) * 1024 + s0 + r] = s.x + qbv.x;
    lg[(size_t)(b * 16 + n0 + 1) * 1024 + s0 + r] = s.y + qbv.y;
    lg[(size_t)(b * 16 + n0 + 2) * 1024 + s0 + r] = s.z + qbv.z;
    lg[(size_t)(b * 16 + n0 + 3) * 1024 + s0 + r] = s.w + qbv.w;
  }
}

// ---------------- K3: softmax stats + exp (transposed write) ----------------
__global__ __launch_bounds__(256) void k_softmax(const float* __restrict__ lg,
                                                 float* __restrict__ es,
                                                 float* __restrict__ lsum) {
  const int bi = blockIdx.x;  // b*16+n, 512 blocks
  const int b = bi >> 4, n = bi & 15;
  const int tid = threadIdx.x;
  __shared__ float red[256];

  const float4 lv = *(const float4*)(lg + (size_t)bi * 1024 + tid * 4);
  float lm = fmaxf(fmaxf(lv.x, lv.y), fmaxf(lv.z, lv.w));
  red[tid] = lm; __syncthreads();
  for (int off = 128; off; off >>= 1) {
    if (tid < off) red[tid] = fmaxf(red[tid], red[tid + off]);
    __syncthreads();
  }
  const float m = red[0];
  __syncthreads();

  const float e0 = __expf(lv.x - m), e1 = __expf(lv.y - m);
  const float e2 = __expf(lv.z - m), e3 = __expf(lv.w - m);
  red[tid] = (e0 + e1) + (e2 + e3); __syncthreads();
  for (int off = 128; off; off >>= 1) {
    if (tid < off) red[tid] += red[tid + off];
    __syncthreads();
  }
  if (tid == 0) lsum[bi] = red[0];

  const size_t eb = ((size_t)b * 1024 + tid * 4) * 16 + n;  // es[b][s][n]
  es[eb] = e0; es[eb + 16] = e1; es[eb + 32] = e2; es[eb + 48] = e3;
}

// ---------------- K4: wp[b][ch][n][c] = sum_s e*x ----------------
__global__ __launch_bounds__(1024) void k_wsum(const float* __restrict__ x,
                                               const float* __restrict__ es,
                                               float* __restrict__ wp) {
  const int b = blockIdx.x >> 3, ch = blockIdx.x & 7;  // 256 blocks
  const int tid = threadIdx.x;
  const int lane = tid & 63, wid = tid >> 6;
  const int q = wid & 3, sub = wid >> 2;  // c-quarter, s-subchunk
  __shared__ float wl[16 * 1024];  // 64 KB

  for (int i = tid; i < 16 * 1024; i += 1024) wl[i] = 0.f;
  __syncthreads();

  float acc[16][4];
#pragma unroll
  for (int n = 0; n < 16; n++)
#pragma unroll
    for (int k = 0; k < 4; k++) acc[n][k] = 0.f;

  const int c0 = q * 256 + lane;
  for (int si = 0; si < 32; si++) {
    const int s = ch * 128 + sub * 32 + si;
    const float* xp = x + (size_t)(b * 1024 + s) * 1024;
    const float xk0 = xp[c0], xk1 = xp[c0 + 64], xk2 = xp[c0 + 128], xk3 = xp[c0 + 192];
    float4 e4[4];
    const float4* ep = (const float4*)(es + (size_t)(b * 1024 + s) * 16);
#pragma unroll
    for (int j = 0; j < 4; j++) e4[j] = ep[j];
#pragma unroll
    for (int n = 0; n < 16; n++) {
      const float ev = ((const float*)e4)[n];
      acc[n][0] += ev * xk0; acc[n][1] += ev * xk1;
      acc[n][2] += ev * xk2; acc[n][3] += ev * xk3;
    }
  }

  // phased non-atomic LDS accumulate (deterministic; lane-consecutive -> conflict-free)
  for (int ph = 0; ph < 4; ph++) {
    if (sub == ph) {
#pragma unroll
      for (int n = 0; n < 16; n++) {
        wl[n * 1024 + c0]       += acc[n][0];
        wl[n * 1024 + c0 + 64]  += acc[n][1];
        wl[n * 1024 + c0 + 128] += acc[n][2];
        wl[n * 1024 + c0 + 192] += acc[n][3];
      }
    }
    __syncthreads();
  }

  float* wpb = wp + (size_t)blockIdx.x * 16384;
  for (int i = tid; i < 16384; i += 1024) wpb[i] = wl[i];
}

// ---------------- K5: out = (w . vk)/l + vb ----------------
__global__ __launch_bounds__(256) void k_out(const float* __restrict__ wp,
                                             const float* __restrict__ vk,
                                             const float* __restrict__ vb,
                                             const float* __restrict__ lsum,
                                             float* __restrict__ out) {
  const int bi = blockIdx.x;  // b*16+n, 512 blocks
  const int b = bi >> 4, n = bi & 15;
  const int tid = threadIdx.x;
  __shared__ float wrow[1024];
  __shared__ float red[4][64];

  float4 a4 = {0.f, 0.f, 0.f, 0.f};
#pragma unroll
  for (int ch = 0; ch < 8; ch++) {
    const float4 t = *(const float4*)(wp + ((size_t)(b * 8 + ch) * 16 + n) * 1024 + tid * 4);
    a4.x += t.x; a4.y += t.y; a4.z += t.z; a4.w += t.w;
  }
  *(float4*)&wrow[tid * 4] = a4;
  __syncthreads();

  const int v = tid & 63, cq = tid >> 6;
  float a = 0.f;
  const float* vkc = vk + n * 64 + v;
  for (int ci = 0; ci < 256; ci++) {
    const int c = cq * 256 + ci;
    a += wrow[c] * vkc[(size_t)c * 1024];
  }
  red[cq][v] = a;
  __syncthreads();
  if (tid < 64) {
    const float o = (red[0][tid] + red[1][tid] + red[2][tid] + red[3][tid]) / lsum[bi]
                    + vb[n * 64 + tid];
    out[(size_t)b * 1024 + n * 64 + tid] = o;
  }
}

extern "C" void kernel_launch(void* const* d_in, const int* in_sizes, int n_in,
                              void* d_out, int out_size, void* d_ws, size_t ws_size,
                              hipStream_t stream) {
  const float* x  = (const float*)d_in[0];  // key_value [32,32,32,1024]
  const float* q  = (const float*)d_in[1];  // query [1,1,16,64]
  const float* kk = (const float*)d_in[2];  // k_kernel [1024,1024]
  const float* kb = (const float*)d_in[3];  // k_bias [1024]
  const float* vk = (const float*)d_in[4];  // v_kernel [1024,1024]
  const float* vb = (const float*)d_in[5];  // v_bias [1024]
  float* out = (float*)d_out;               // [32,16,64] fp32

  float* f   = (float*)d_ws;
  float* qk  = f;            // 16384
  float* qb  = f + 16384;    // 16
  float* ls  = f + 16400;    // 512
  float* lg  = f + 32768;    // 524288  logits_t[b][n][s]
  float* es  = f + 557056;   // 524288  e[b][s][n]
  float* wp  = f + 1081344;  // 4194304 wp[b][ch][n][c]   (total ~21.1 MB)

  hipLaunchKernelGGL(k_qk,      dim3(64),   dim3(256),  0, stream, kk, q, kb, qk, qb);
  hipLaunchKernelGGL(k_logits,  dim3(512),  dim3(256),  0, stream, x, qk, qb, lg);
  hipLaunchKernelGGL(k_softmax, dim3(512),  dim3(256),  0, stream, lg, es, ls);
  hipLaunchKernelGGL(k_wsum,    dim3(256),  dim3(1024), 0, stream, x, es, wp);
  hipLaunchKernelGGL(k_out,     dim3(512),  dim3(256),  0, stream, wp, vk, vb, ls, out);
}